// Round 10
// baseline (923.285 us; speedup 1.0000x reference)
//
#include <hip/hip_runtime.h>

// SOM BMU one-hot via split-bf16 MFMA GEMM. R10 = R9 + MEASUREMENT:
// som_main launched TWICE (idempotent) -- dur_R10 - dur_R9 isolates main's
// true per-iteration cost, which hides below the 257 us poison-fill in
// rocprof top-5. flag zeroing folded into prep (one fewer dispatch).
//
// Accounting so far: 660 = fill 257 + restore ~16 + prep ~10 + M + P + gaps,
// with bottom-up models M~100, P~20 -- ~250 us unplaced. This round buys the
// number that decides the next lever.

typedef __attribute__((ext_vector_type(8))) short bf16x8;   // 8 bf16 = 4 VGPR
typedef __attribute__((ext_vector_type(4))) float f32x4;

#define SOM_K 1024
#define SOM_D 128
#define MARGIN 0.02f
#define FLAG_CAP 8192

// d_ws layout (bytes):
#define WS_WSQ   64        // 1024 f32  (4 KB)
#define WS_W3    8192      // 64 tiles x 8 slots x 64 lanes x 8 bf16 (512 KB)
#define WS_FLAGS 532480    // 8192 int  (32 KB) -> ends ~565 KB

static __device__ __forceinline__ unsigned short f2bf(float f) {
    unsigned u = __float_as_uint(f);
    return (unsigned short)((u + 0x7FFFu + ((u >> 16) & 1u)) >> 16);  // RNE
}
static __device__ __forceinline__ float bf2f(unsigned short h) {
    return __uint_as_float(((unsigned)h) << 16);
}

// ---- prep: w -> w3 (swizzled split-bf16, 8 slots) + exact wsq + flag=0 ----
__global__ __launch_bounds__(256) void som_prep(
    const float* __restrict__ w, unsigned short* __restrict__ w3,
    float* __restrict__ wsq, int* __restrict__ flag_count)
{
    __shared__ float ws_[16][SOM_D];     // 8 KB staging for 16 protos
    const int nt = blockIdx.x;           // tile 0..63
    const int tid = threadIdx.x;

    if (nt == 0 && tid == 0) *flag_count = 0;   // replaces memsetAsync

    const float* src = w + (size_t)nt * 16 * SOM_D;
    #pragma unroll
    for (int r = 0; r < 8; ++r) {
        const int e = r * 256 + tid;
        ws_[e >> 7][e & 127] = src[e];
    }
    __syncthreads();

    unsigned short* dst = w3 + (size_t)nt * 4096;
    #pragma unroll
    for (int r = 0; r < 2; ++r) {
        const int G = r * 256 + tid;     // 0..511
        const int s = G >> 6;            // slot 0..7
        const int l = G & 63;            // lane
        const int c = l & 15, q = l >> 4;
        bf16x8 v;
        #pragma unroll
        for (int j = 0; j < 8; ++j) {
            const int kk = 32 * s + 8 * q + j;       // 0..255
            const int d = kk & 127;
            const float f = ws_[c][d];
            const unsigned short h = f2bf(f);
            v[j] = (short)((kk & 128) ? f2bf(f - bf2f(h)) : h);  // wl : wh
        }
        *(bf16x8*)(dst + G * 8) = v;
    }

    if (tid < 16) {
        double s = 0.0;
        #pragma unroll 16
        for (int d = 0; d < SOM_D; ++d) {
            double v = (double)ws_[tid][d];
            s += v * v;
        }
        wsq[nt * 16 + tid] = (float)s;
    }
}

// ---- main: 4 waves/block share B stream; MFMA + argmin + one-hot ----------
__global__ __launch_bounds__(256, 2) void som_main(
    const float* __restrict__ x,
    const unsigned short* __restrict__ w3,
    const float* __restrict__ wsq,
    float* __restrict__ out,
    int* __restrict__ flag_count,
    int* __restrict__ flag_list,
    int n_samples)
{
    const int lane = threadIdx.x & 63;
    const int wv   = threadIdx.x >> 6;       // wave 0..3
    const int c = lane & 15;
    const int q = lane >> 4;
    const int R0 = blockIdx.x * 128 + wv * 32;   // 782 blocks x 128 rows

    // a-frags: A[m=lane&15][k=8q+j], two 16-row groups, hi+lo (64 VGPR).
    bf16x8 ah[2][4], al[2][4];
    #pragma unroll
    for (int g = 0; g < 2; ++g) {
        int row = R0 + 16 * g + c;
        if (row >= n_samples) row = n_samples - 1;   // clamp (results unused)
        const float* xp = x + (size_t)row * SOM_D + 8 * q;
        #pragma unroll
        for (int s = 0; s < 4; ++s) {
            float4 v0 = *(const float4*)(xp + 32 * s);
            float4 v1 = *(const float4*)(xp + 32 * s + 4);
            float xv[8] = {v0.x, v0.y, v0.z, v0.w, v1.x, v1.y, v1.z, v1.w};
            bf16x8 hh, ll;
            #pragma unroll
            for (int j = 0; j < 8; ++j) {
                unsigned short h = f2bf(xv[j]);
                hh[j] = (short)h;
                ll[j] = (short)f2bf(xv[j] - bf2f(h));
            }
            ah[g][s] = hh; al[g][s] = ll;
        }
    }

    float best[2][4], sec[2][4];
    int bk[2][4];
    #pragma unroll
    for (int g = 0; g < 2; ++g)
        #pragma unroll
        for (int r = 0; r < 4; ++r) { best[g][r] = 1e30f; sec[g][r] = 1e30f; bk[g][r] = 0; }

    const unsigned short* wbase = w3 + lane * 8;

    #pragma unroll 1
    for (int nt = 0; nt < 64; ++nt) {
        const int n0 = nt * 16;
        const unsigned short* wp = wbase + (size_t)nt * 4096;
        bf16x8 b[8];
        #pragma unroll
        for (int s = 0; s < 8; ++s) b[s] = *(const bf16x8*)(wp + 512 * s);
        const float wq = wsq[n0 + c];

        f32x4 a0 = {0.f, 0.f, 0.f, 0.f}, a1 = {0.f, 0.f, 0.f, 0.f};
        #pragma unroll
        for (int s = 0; s < 4; ++s) {   // xh * wh
            a0 = __builtin_amdgcn_mfma_f32_16x16x32_bf16(ah[0][s], b[s], a0, 0, 0, 0);
            a1 = __builtin_amdgcn_mfma_f32_16x16x32_bf16(ah[1][s], b[s], a1, 0, 0, 0);
        }
        #pragma unroll
        for (int s = 0; s < 4; ++s) {   // xh * wl
            a0 = __builtin_amdgcn_mfma_f32_16x16x32_bf16(ah[0][s], b[4 + s], a0, 0, 0, 0);
            a1 = __builtin_amdgcn_mfma_f32_16x16x32_bf16(ah[1][s], b[4 + s], a1, 0, 0, 0);
        }
        #pragma unroll
        for (int s = 0; s < 4; ++s) {   // xl * wh -- reuses b[0..3]
            a0 = __builtin_amdgcn_mfma_f32_16x16x32_bf16(al[0][s], b[s], a0, 0, 0, 0);
            a1 = __builtin_amdgcn_mfma_f32_16x16x32_bf16(al[1][s], b[s], a1, 0, 0, 0);
        }

        #pragma unroll
        for (int r = 0; r < 4; ++r) {
            float s0 = wq - 2.f * a0[r];
            if (s0 < best[0][r]) { sec[0][r] = best[0][r]; best[0][r] = s0; bk[0][r] = n0 + c; }
            else if (s0 < sec[0][r]) sec[0][r] = s0;
            float s1 = wq - 2.f * a1[r];
            if (s1 < best[1][r]) { sec[1][r] = best[1][r]; best[1][r] = s1; bk[1][r] = n0 + c; }
            else if (s1 < sec[1][r]) sec[1][r] = s1;
        }
    }

    // reduce across the 16 c-lanes of each quad-group (result in all lanes)
    #pragma unroll
    for (int g = 0; g < 2; ++g) {
        #pragma unroll
        for (int r = 0; r < 4; ++r) {
            float b0v = best[g][r], s0v = sec[g][r];
            int k0 = bk[g][r];
            #pragma unroll
            for (int m = 1; m < 16; m <<= 1) {
                float ob = __shfl_xor(b0v, m);
                float os = __shfl_xor(s0v, m);
                int   ok = __shfl_xor(k0, m);
                if (ob < b0v || (ob == b0v && ok < k0)) {
                    s0v = fminf(b0v, os); b0v = ob; k0 = ok;
                } else {
                    s0v = fminf(s0v, ob);
                }
            }
            best[g][r] = b0v; sec[g][r] = s0v; bk[g][r] = k0;
        }
    }

    if (c == 0) {   // lanes 0,16,32,48 hold rows g*16 + 4q + r
        #pragma unroll
        for (int g = 0; g < 2; ++g) {
            #pragma unroll
            for (int r = 0; r < 4; ++r) {
                const int row = R0 + g * 16 + 4 * q + r;
                if (row < n_samples && (sec[g][r] - best[g][r]) < MARGIN) {
                    int i = atomicAdd(flag_count, 1);
                    if (i < FLAG_CAP) flag_list[i] = row;
                }
            }
        }
    }

    // fused one-hot write: row rr's bmu lives in quad (rr>>2)&3, reg rr&3
    #pragma unroll 1
    for (int rr = 0; rr < 32; ++rr) {
        const int row = R0 + rr;
        if (row >= n_samples) break;     // tail guard (rows are ascending)
        const int g = rr >> 4, qq = (rr >> 2) & 3, r = rr & 3;
        const int b = __shfl(bk[g][r], qq << 4);
        f32x4* op = (f32x4*)(out + (size_t)row * SOM_K);
        #pragma unroll
        for (int j = 0; j < 4; ++j) {
            const int e = j * 64 + lane;
            f32x4 v = {0.f, 0.f, 0.f, 0.f};
            if ((b >> 2) == e) v[b & 3] = 1.0f;
            __builtin_nontemporal_store(v, op + e);
        }
    }
}

// ---- pass2: fp64 re-solve, one 1024-thread block per flagged row ----------
__global__ __launch_bounds__(1024) void som_pass2(
    const float* __restrict__ x,
    const float* __restrict__ w,
    float* __restrict__ out,
    const int* __restrict__ flag_count,
    const int* __restrict__ flag_list)
{
    __shared__ float xs[SOM_D];
    __shared__ double rbest[16];
    __shared__ int    rk[16];

    const int tid  = threadIdx.x;          // == proto k
    const int lane = tid & 63;
    const int wv   = tid >> 6;             // wave 0..15
    int cnt = *flag_count;
    if (cnt > FLAG_CAP) cnt = FLAG_CAP;

    for (int i = blockIdx.x; i < cnt; i += gridDim.x) {
        const int row = flag_list[i];
        __syncthreads();                   // guard xs/red reuse
        if (tid < SOM_D) xs[tid] = x[(size_t)row * SOM_D + tid];
        __syncthreads();

        const float* wk = w + (size_t)tid * SOM_D;
        double s0 = 0.0, s1 = 0.0;
        #pragma unroll
        for (int d = 0; d < SOM_D; d += 4) {
            float4 wv4 = *(const float4*)(wk + d);
            double w0 = (double)wv4.x, w1 = (double)wv4.y;
            double w2 = (double)wv4.z, w3 = (double)wv4.w;
            s0 += w0 * (w0 - 2.0 * (double)xs[d])     + w2 * (w2 - 2.0 * (double)xs[d + 2]);
            s1 += w1 * (w1 - 2.0 * (double)xs[d + 1]) + w3 * (w3 - 2.0 * (double)xs[d + 3]);
        }
        double sc = s0 + s1;
        int bk = tid;

        #pragma unroll
        for (int off = 32; off > 0; off >>= 1) {
            double os = __shfl_down(sc, off);
            int    ok = __shfl_down(bk, off);
            if (os < sc || (os == sc && ok < bk)) { sc = os; bk = ok; }
        }
        if (lane == 0) { rbest[wv] = sc; rk[wv] = bk; }
        __syncthreads();

        if (tid == 0) {
            double b = rbest[0]; int k0 = rk[0];
            #pragma unroll
            for (int v = 1; v < 16; ++v) {
                if (rbest[v] < b || (rbest[v] == b && rk[v] < k0)) { b = rbest[v]; k0 = rk[v]; }
            }
            rk[0] = k0;
        }
        __syncthreads();
        const int bmu = rk[0];

        out[(size_t)row * SOM_K + tid] = (tid == bmu) ? 1.0f : 0.0f;
    }
}

extern "C" void kernel_launch(void* const* d_in, const int* in_sizes, int n_in,
                              void* d_out, int out_size, void* d_ws, size_t ws_size,
                              hipStream_t stream) {
    const float* x = (const float*)d_in[0];
    const float* w = (const float*)d_in[1];
    float* out = (float*)d_out;

    const int n_samples = in_sizes[0] / SOM_D;  // 100000

    char* ws = (char*)d_ws;
    int*            flag_count = (int*)ws;
    float*          wsq        = (float*)(ws + WS_WSQ);
    unsigned short* w3         = (unsigned short*)(ws + WS_W3);
    int*            flag_list  = (int*)(ws + WS_FLAGS);

    som_prep<<<64, 256, 0, stream>>>(w, w3, wsq, flag_count);
    const int grid = (n_samples + 127) / 128;    // 782
    // MEASUREMENT: launch twice (idempotent). dur delta vs R9 == main's cost.
    som_main<<<grid, 256, 0, stream>>>(x, w3, wsq, out, flag_count, flag_list,
                                       n_samples);
    som_main<<<grid, 256, 0, stream>>>(x, w3, wsq, out, flag_count, flag_list,
                                       n_samples);
    som_pass2<<<256, 1024, 0, stream>>>(x, w, out, flag_count, flag_list);
}

// Round 11
// 689.203 us; speedup vs baseline: 1.3396x; 1.3396x over previous
//
#include <hip/hip_runtime.h>

// SOM BMU one-hot via split-bf16 MFMA GEMM. R11 = R9 structure with:
//   (a) __launch_bounds__(256,3): 12 waves/CU (was 8) -- compute phase is
//       latency-bound (R5: MfmaUtil 9.4%; R6/R8/R9 BW cuts all neutral),
//       so TLP is the lever. Live VGPR ~150 < 168 cap @3 waves/SIMD.
//   (b) plain dwordx4 one-hot stores (NT stores unproven vs m13's 6.3 TB/s
//       plain-store ceiling; fillBuffer streams 6.3 TB/s with plain stores).
// R10 measurement: main ~255-265 us (= dominant controllable cost; floor
// ~100 = 33 MFMA-issue + 67 write). Budget: fill 257 + restore 8 + prep 10
// + main 255 + pass2 35 + gaps 25 = 660.

typedef __attribute__((ext_vector_type(8))) short bf16x8;   // 8 bf16 = 4 VGPR
typedef __attribute__((ext_vector_type(4))) float f32x4;

#define SOM_K 1024
#define SOM_D 128
#define MARGIN 0.02f
#define FLAG_CAP 8192

// d_ws layout (bytes):
#define WS_WSQ   64        // 1024 f32  (4 KB)
#define WS_W3    8192      // 64 tiles x 8 slots x 64 lanes x 8 bf16 (512 KB)
#define WS_FLAGS 532480    // 8192 int  (32 KB) -> ends ~565 KB

static __device__ __forceinline__ unsigned short f2bf(float f) {
    unsigned u = __float_as_uint(f);
    return (unsigned short)((u + 0x7FFFu + ((u >> 16) & 1u)) >> 16);  // RNE
}
static __device__ __forceinline__ float bf2f(unsigned short h) {
    return __uint_as_float(((unsigned)h) << 16);
}

// ---- prep: w -> w3 (swizzled split-bf16, 8 slots) + exact wsq + flag=0 ----
__global__ __launch_bounds__(256) void som_prep(
    const float* __restrict__ w, unsigned short* __restrict__ w3,
    float* __restrict__ wsq, int* __restrict__ flag_count)
{
    __shared__ float ws_[16][SOM_D];     // 8 KB staging for 16 protos
    const int nt = blockIdx.x;           // tile 0..63
    const int tid = threadIdx.x;

    if (nt == 0 && tid == 0) *flag_count = 0;

    const float* src = w + (size_t)nt * 16 * SOM_D;
    #pragma unroll
    for (int r = 0; r < 8; ++r) {
        const int e = r * 256 + tid;
        ws_[e >> 7][e & 127] = src[e];
    }
    __syncthreads();

    unsigned short* dst = w3 + (size_t)nt * 4096;
    #pragma unroll
    for (int r = 0; r < 2; ++r) {
        const int G = r * 256 + tid;     // 0..511
        const int s = G >> 6;            // slot 0..7
        const int l = G & 63;            // lane
        const int c = l & 15, q = l >> 4;
        bf16x8 v;
        #pragma unroll
        for (int j = 0; j < 8; ++j) {
            const int kk = 32 * s + 8 * q + j;       // 0..255
            const int d = kk & 127;
            const float f = ws_[c][d];
            const unsigned short h = f2bf(f);
            v[j] = (short)((kk & 128) ? f2bf(f - bf2f(h)) : h);  // wl : wh
        }
        *(bf16x8*)(dst + G * 8) = v;
    }

    if (tid < 16) {
        double s = 0.0;
        #pragma unroll 16
        for (int d = 0; d < SOM_D; ++d) {
            double v = (double)ws_[tid][d];
            s += v * v;
        }
        wsq[nt * 16 + tid] = (float)s;
    }
}

// ---- main: 4 waves/block share B stream; MFMA + argmin + one-hot ----------
__global__ __launch_bounds__(256, 3) void som_main(
    const float* __restrict__ x,
    const unsigned short* __restrict__ w3,
    const float* __restrict__ wsq,
    float* __restrict__ out,
    int* __restrict__ flag_count,
    int* __restrict__ flag_list,
    int n_samples)
{
    const int lane = threadIdx.x & 63;
    const int wv   = threadIdx.x >> 6;       // wave 0..3
    const int c = lane & 15;
    const int q = lane >> 4;
    const int R0 = blockIdx.x * 128 + wv * 32;   // 782 blocks x 128 rows

    // a-frags: A[m=lane&15][k=8q+j], two 16-row groups, hi+lo (64 VGPR).
    bf16x8 ah[2][4], al[2][4];
    #pragma unroll
    for (int g = 0; g < 2; ++g) {
        int row = R0 + 16 * g + c;
        if (row >= n_samples) row = n_samples - 1;   // clamp (results unused)
        const float* xp = x + (size_t)row * SOM_D + 8 * q;
        #pragma unroll
        for (int s = 0; s < 4; ++s) {
            float4 v0 = *(const float4*)(xp + 32 * s);
            float4 v1 = *(const float4*)(xp + 32 * s + 4);
            float xv[8] = {v0.x, v0.y, v0.z, v0.w, v1.x, v1.y, v1.z, v1.w};
            bf16x8 hh, ll;
            #pragma unroll
            for (int j = 0; j < 8; ++j) {
                unsigned short h = f2bf(xv[j]);
                hh[j] = (short)h;
                ll[j] = (short)f2bf(xv[j] - bf2f(h));
            }
            ah[g][s] = hh; al[g][s] = ll;
        }
    }

    float best[2][4], sec[2][4];
    int bk[2][4];
    #pragma unroll
    for (int g = 0; g < 2; ++g)
        #pragma unroll
        for (int r = 0; r < 4; ++r) { best[g][r] = 1e30f; sec[g][r] = 1e30f; bk[g][r] = 0; }

    const unsigned short* wbase = w3 + lane * 8;

    #pragma unroll 1
    for (int nt = 0; nt < 64; ++nt) {
        const int n0 = nt * 16;
        const unsigned short* wp = wbase + (size_t)nt * 4096;
        bf16x8 b[8];
        #pragma unroll
        for (int s = 0; s < 8; ++s) b[s] = *(const bf16x8*)(wp + 512 * s);
        const float wq = wsq[n0 + c];

        f32x4 a0 = {0.f, 0.f, 0.f, 0.f}, a1 = {0.f, 0.f, 0.f, 0.f};
        #pragma unroll
        for (int s = 0; s < 4; ++s) {   // xh * wh
            a0 = __builtin_amdgcn_mfma_f32_16x16x32_bf16(ah[0][s], b[s], a0, 0, 0, 0);
            a1 = __builtin_amdgcn_mfma_f32_16x16x32_bf16(ah[1][s], b[s], a1, 0, 0, 0);
        }
        #pragma unroll
        for (int s = 0; s < 4; ++s) {   // xh * wl
            a0 = __builtin_amdgcn_mfma_f32_16x16x32_bf16(ah[0][s], b[4 + s], a0, 0, 0, 0);
            a1 = __builtin_amdgcn_mfma_f32_16x16x32_bf16(ah[1][s], b[4 + s], a1, 0, 0, 0);
        }
        #pragma unroll
        for (int s = 0; s < 4; ++s) {   // xl * wh -- reuses b[0..3]
            a0 = __builtin_amdgcn_mfma_f32_16x16x32_bf16(al[0][s], b[s], a0, 0, 0, 0);
            a1 = __builtin_amdgcn_mfma_f32_16x16x32_bf16(al[1][s], b[s], a1, 0, 0, 0);
        }

        #pragma unroll
        for (int r = 0; r < 4; ++r) {
            float s0 = wq - 2.f * a0[r];
            if (s0 < best[0][r]) { sec[0][r] = best[0][r]; best[0][r] = s0; bk[0][r] = n0 + c; }
            else if (s0 < sec[0][r]) sec[0][r] = s0;
            float s1 = wq - 2.f * a1[r];
            if (s1 < best[1][r]) { sec[1][r] = best[1][r]; best[1][r] = s1; bk[1][r] = n0 + c; }
            else if (s1 < sec[1][r]) sec[1][r] = s1;
        }
    }

    // reduce across the 16 c-lanes of each quad-group (result in all lanes)
    #pragma unroll
    for (int g = 0; g < 2; ++g) {
        #pragma unroll
        for (int r = 0; r < 4; ++r) {
            float b0v = best[g][r], s0v = sec[g][r];
            int k0 = bk[g][r];
            #pragma unroll
            for (int m = 1; m < 16; m <<= 1) {
                float ob = __shfl_xor(b0v, m);
                float os = __shfl_xor(s0v, m);
                int   ok = __shfl_xor(k0, m);
                if (ob < b0v || (ob == b0v && ok < k0)) {
                    s0v = fminf(b0v, os); b0v = ob; k0 = ok;
                } else {
                    s0v = fminf(s0v, ob);
                }
            }
            best[g][r] = b0v; sec[g][r] = s0v; bk[g][r] = k0;
        }
    }

    if (c == 0) {   // lanes 0,16,32,48 hold rows g*16 + 4q + r
        #pragma unroll
        for (int g = 0; g < 2; ++g) {
            #pragma unroll
            for (int r = 0; r < 4; ++r) {
                const int row = R0 + g * 16 + 4 * q + r;
                if (row < n_samples && (sec[g][r] - best[g][r]) < MARGIN) {
                    int i = atomicAdd(flag_count, 1);
                    if (i < FLAG_CAP) flag_list[i] = row;
                }
            }
        }
    }

    // fused one-hot write (plain dwordx4 stores)
    #pragma unroll 1
    for (int rr = 0; rr < 32; ++rr) {
        const int row = R0 + rr;
        if (row >= n_samples) break;     // tail guard (rows are ascending)
        const int g = rr >> 4, qq = (rr >> 2) & 3, r = rr & 3;
        const int b = __shfl(bk[g][r], qq << 4);
        f32x4* op = (f32x4*)(out + (size_t)row * SOM_K);
        #pragma unroll
        for (int j = 0; j < 4; ++j) {
            const int e = j * 64 + lane;
            f32x4 v = {0.f, 0.f, 0.f, 0.f};
            if ((b >> 2) == e) v[b & 3] = 1.0f;
            op[e] = v;
        }
    }
}

// ---- pass2: fp64 re-solve, one 1024-thread block per flagged row ----------
__global__ __launch_bounds__(1024) void som_pass2(
    const float* __restrict__ x,
    const float* __restrict__ w,
    float* __restrict__ out,
    const int* __restrict__ flag_count,
    const int* __restrict__ flag_list)
{
    __shared__ float xs[SOM_D];
    __shared__ double rbest[16];
    __shared__ int    rk[16];

    const int tid  = threadIdx.x;          // == proto k
    const int lane = tid & 63;
    const int wv   = tid >> 6;             // wave 0..15
    int cnt = *flag_count;
    if (cnt > FLAG_CAP) cnt = FLAG_CAP;

    for (int i = blockIdx.x; i < cnt; i += gridDim.x) {
        const int row = flag_list[i];
        __syncthreads();                   // guard xs/red reuse
        if (tid < SOM_D) xs[tid] = x[(size_t)row * SOM_D + tid];
        __syncthreads();

        const float* wk = w + (size_t)tid * SOM_D;
        double s0 = 0.0, s1 = 0.0;
        #pragma unroll
        for (int d = 0; d < SOM_D; d += 4) {
            float4 wv4 = *(const float4*)(wk + d);
            double w0 = (double)wv4.x, w1 = (double)wv4.y;
            double w2 = (double)wv4.z, w3 = (double)wv4.w;
            s0 += w0 * (w0 - 2.0 * (double)xs[d])     + w2 * (w2 - 2.0 * (double)xs[d + 2]);
            s1 += w1 * (w1 - 2.0 * (double)xs[d + 1]) + w3 * (w3 - 2.0 * (double)xs[d + 3]);
        }
        double sc = s0 + s1;
        int bk = tid;

        #pragma unroll
        for (int off = 32; off > 0; off >>= 1) {
            double os = __shfl_down(sc, off);
            int    ok = __shfl_down(bk, off);
            if (os < sc || (os == sc && ok < bk)) { sc = os; bk = ok; }
        }
        if (lane == 0) { rbest[wv] = sc; rk[wv] = bk; }
        __syncthreads();

        if (tid == 0) {
            double b = rbest[0]; int k0 = rk[0];
            #pragma unroll
            for (int v = 1; v < 16; ++v) {
                if (rbest[v] < b || (rbest[v] == b && rk[v] < k0)) { b = rbest[v]; k0 = rk[v]; }
            }
            rk[0] = k0;
        }
        __syncthreads();
        const int bmu = rk[0];

        out[(size_t)row * SOM_K + tid] = (tid == bmu) ? 1.0f : 0.0f;
    }
}

extern "C" void kernel_launch(void* const* d_in, const int* in_sizes, int n_in,
                              void* d_out, int out_size, void* d_ws, size_t ws_size,
                              hipStream_t stream) {
    const float* x = (const float*)d_in[0];
    const float* w = (const float*)d_in[1];
    float* out = (float*)d_out;

    const int n_samples = in_sizes[0] / SOM_D;  // 100000

    char* ws = (char*)d_ws;
    int*            flag_count = (int*)ws;
    float*          wsq        = (float*)(ws + WS_WSQ);
    unsigned short* w3         = (unsigned short*)(ws + WS_W3);
    int*            flag_list  = (int*)(ws + WS_FLAGS);

    som_prep<<<64, 256, 0, stream>>>(w, w3, wsq, flag_count);
    const int grid = (n_samples + 127) / 128;    // 782
    som_main<<<grid, 256, 0, stream>>>(x, w3, wsq, out, flag_count, flag_list,
                                       n_samples);
    som_pass2<<<256, 1024, 0, stream>>>(x, w, out, flag_count, flag_list);
}

// Round 12
// 661.417 us; speedup vs baseline: 1.3959x; 1.0420x over previous
//
#include <hip/hip_runtime.h>

// SOM BMU one-hot via split-bf16 MFMA GEMM. R12: TLP round.
// R11 evidence: main is ~75% memory-latency stall (MfmaUtil 11.8, VALU 18.6,
// Occ 18% = 6 waves/CU resident; LDS-spill + 2M bank conflicts was FREE).
// Fix: 16 samples/wave (live VGPR ~110, was ~150+), grid 1563 (was 782),
// NO min-waves launch_bounds (R11: it spills; R9: it caps blocks/CU).
// Target: 16-20 resident waves/CU -> compute phase issue-bound.
//   som_prep : w -> w3 (8-slot swizzled B-frags [wh x4|wl x4]) + wsq + flag=0
//   som_main : 4 waves/block share B; 16 samples/wave; two-chain MFMA acc
//   som_pass2: fp64 re-solve, one 1024-thread block per flagged row

typedef __attribute__((ext_vector_type(8))) short bf16x8;   // 8 bf16 = 4 VGPR
typedef __attribute__((ext_vector_type(4))) float f32x4;

#define SOM_K 1024
#define SOM_D 128
#define MARGIN 0.02f
#define FLAG_CAP 8192

// d_ws layout (bytes):
#define WS_WSQ   64        // 1024 f32  (4 KB)
#define WS_W3    8192      // 64 tiles x 8 slots x 64 lanes x 8 bf16 (512 KB)
#define WS_FLAGS 532480    // 8192 int  (32 KB) -> ends ~565 KB

static __device__ __forceinline__ unsigned short f2bf(float f) {
    unsigned u = __float_as_uint(f);
    return (unsigned short)((u + 0x7FFFu + ((u >> 16) & 1u)) >> 16);  // RNE
}
static __device__ __forceinline__ float bf2f(unsigned short h) {
    return __uint_as_float(((unsigned)h) << 16);
}

// ---- prep: w -> w3 (swizzled split-bf16, 8 slots) + exact wsq + flag=0 ----
__global__ __launch_bounds__(256) void som_prep(
    const float* __restrict__ w, unsigned short* __restrict__ w3,
    float* __restrict__ wsq, int* __restrict__ flag_count)
{
    __shared__ float ws_[16][SOM_D];     // 8 KB staging for 16 protos
    const int nt = blockIdx.x;           // tile 0..63
    const int tid = threadIdx.x;

    if (nt == 0 && tid == 0) *flag_count = 0;

    const float* src = w + (size_t)nt * 16 * SOM_D;
    #pragma unroll
    for (int r = 0; r < 8; ++r) {
        const int e = r * 256 + tid;
        ws_[e >> 7][e & 127] = src[e];
    }
    __syncthreads();

    unsigned short* dst = w3 + (size_t)nt * 4096;
    #pragma unroll
    for (int r = 0; r < 2; ++r) {
        const int G = r * 256 + tid;     // 0..511
        const int s = G >> 6;            // slot 0..7
        const int l = G & 63;            // lane
        const int c = l & 15, q = l >> 4;
        bf16x8 v;
        #pragma unroll
        for (int j = 0; j < 8; ++j) {
            const int kk = 32 * s + 8 * q + j;       // 0..255
            const int d = kk & 127;
            const float f = ws_[c][d];
            const unsigned short h = f2bf(f);
            v[j] = (short)((kk & 128) ? f2bf(f - bf2f(h)) : h);  // wl : wh
        }
        *(bf16x8*)(dst + G * 8) = v;
    }

    if (tid < 16) {
        double s = 0.0;
        #pragma unroll 16
        for (int d = 0; d < SOM_D; ++d) {
            double v = (double)ws_[tid][d];
            s += v * v;
        }
        wsq[nt * 16 + tid] = (float)s;
    }
}

// ---- main: 16 samples/wave, 4 waves/block share B; MFMA + argmin + write --
__global__ __launch_bounds__(256) void som_main(
    const float* __restrict__ x,
    const unsigned short* __restrict__ w3,
    const float* __restrict__ wsq,
    float* __restrict__ out,
    int* __restrict__ flag_count,
    int* __restrict__ flag_list,
    int n_samples)
{
    const int lane = threadIdx.x & 63;
    const int wv   = threadIdx.x >> 6;       // wave 0..3
    const int c = lane & 15;
    const int q = lane >> 4;
    const int R0 = blockIdx.x * 64 + wv * 16;    // 1563 blocks x 64 rows

    // a-frags: A[m=c][k=8q+j], ONE 16-row group, hi+lo (32 VGPR).
    bf16x8 ah[4], al[4];
    {
        int row = R0 + c;
        if (row >= n_samples) row = n_samples - 1;   // clamp (results unused)
        const float* xp = x + (size_t)row * SOM_D + 8 * q;
        #pragma unroll
        for (int s = 0; s < 4; ++s) {
            float4 v0 = *(const float4*)(xp + 32 * s);
            float4 v1 = *(const float4*)(xp + 32 * s + 4);
            float xv[8] = {v0.x, v0.y, v0.z, v0.w, v1.x, v1.y, v1.z, v1.w};
            bf16x8 hh, ll;
            #pragma unroll
            for (int j = 0; j < 8; ++j) {
                unsigned short h = f2bf(xv[j]);
                hh[j] = (short)h;
                ll[j] = (short)f2bf(xv[j] - bf2f(h));
            }
            ah[s] = hh; al[s] = ll;
        }
    }

    float best[4], sec[4];
    int bk[4];
    #pragma unroll
    for (int r = 0; r < 4; ++r) { best[r] = 1e30f; sec[r] = 1e30f; bk[r] = 0; }

    const unsigned short* wbase = w3 + lane * 8;

    #pragma unroll 1
    for (int nt = 0; nt < 64; ++nt) {
        const int n0 = nt * 16;
        const unsigned short* wp = wbase + (size_t)nt * 4096;
        bf16x8 b[8];
        #pragma unroll
        for (int s = 0; s < 8; ++s) b[s] = *(const bf16x8*)(wp + 512 * s);
        const float wq = wsq[n0 + c];

        // two independent acc chains (depth 8 + depth 4, was 12)
        f32x4 aA = {0.f, 0.f, 0.f, 0.f}, aB = {0.f, 0.f, 0.f, 0.f};
        #pragma unroll
        for (int s = 0; s < 4; ++s)     // xh * wh
            aA = __builtin_amdgcn_mfma_f32_16x16x32_bf16(ah[s], b[s], aA, 0, 0, 0);
        #pragma unroll
        for (int s = 0; s < 4; ++s)     // xh * wl
            aA = __builtin_amdgcn_mfma_f32_16x16x32_bf16(ah[s], b[4 + s], aA, 0, 0, 0);
        #pragma unroll
        for (int s = 0; s < 4; ++s)     // xl * wh -- reuses b[0..3]
            aB = __builtin_amdgcn_mfma_f32_16x16x32_bf16(al[s], b[s], aB, 0, 0, 0);

        #pragma unroll
        for (int r = 0; r < 4; ++r) {
            float s0 = wq - 2.f * (aA[r] + aB[r]);
            if (s0 < best[r]) { sec[r] = best[r]; best[r] = s0; bk[r] = n0 + c; }
            else if (s0 < sec[r]) sec[r] = s0;
        }
    }

    // reduce across the 16 c-lanes of each quad-group (result in all lanes)
    #pragma unroll
    for (int r = 0; r < 4; ++r) {
        float b0v = best[r], s0v = sec[r];
        int k0 = bk[r];
        #pragma unroll
        for (int m = 1; m < 16; m <<= 1) {
            float ob = __shfl_xor(b0v, m);
            float os = __shfl_xor(s0v, m);
            int   ok = __shfl_xor(k0, m);
            if (ob < b0v || (ob == b0v && ok < k0)) {
                s0v = fminf(b0v, os); b0v = ob; k0 = ok;
            } else {
                s0v = fminf(s0v, ob);
            }
        }
        best[r] = b0v; sec[r] = s0v; bk[r] = k0;
    }

    if (c == 0) {   // lanes 0,16,32,48 hold rows 4q + r
        #pragma unroll
        for (int r = 0; r < 4; ++r) {
            const int row = R0 + 4 * q + r;
            if (row < n_samples && (sec[r] - best[r]) < MARGIN) {
                int i = atomicAdd(flag_count, 1);
                if (i < FLAG_CAP) flag_list[i] = row;
            }
        }
    }

    // fused one-hot write: row rr's bmu lives in quad rr>>2, reg rr&3
    #pragma unroll 1
    for (int rr = 0; rr < 16; ++rr) {
        const int row = R0 + rr;
        if (row >= n_samples) break;     // tail guard (rows ascending)
        const int b = __shfl(bk[rr & 3], (rr >> 2) << 4);
        f32x4* op = (f32x4*)(out + (size_t)row * SOM_K);
        #pragma unroll
        for (int j = 0; j < 4; ++j) {
            const int e = j * 64 + lane;
            f32x4 v = {0.f, 0.f, 0.f, 0.f};
            if ((b >> 2) == e) v[b & 3] = 1.0f;
            op[e] = v;
        }
    }
}

// ---- pass2: fp64 re-solve, one 1024-thread block per flagged row ----------
__global__ __launch_bounds__(1024) void som_pass2(
    const float* __restrict__ x,
    const float* __restrict__ w,
    float* __restrict__ out,
    const int* __restrict__ flag_count,
    const int* __restrict__ flag_list)
{
    __shared__ float xs[SOM_D];
    __shared__ double rbest[16];
    __shared__ int    rk[16];

    const int tid  = threadIdx.x;          // == proto k
    const int lane = tid & 63;
    const int wv   = tid >> 6;             // wave 0..15
    int cnt = *flag_count;
    if (cnt > FLAG_CAP) cnt = FLAG_CAP;

    for (int i = blockIdx.x; i < cnt; i += gridDim.x) {
        const int row = flag_list[i];
        __syncthreads();                   // guard xs/red reuse
        if (tid < SOM_D) xs[tid] = x[(size_t)row * SOM_D + tid];
        __syncthreads();

        const float* wk = w + (size_t)tid * SOM_D;
        double s0 = 0.0, s1 = 0.0;
        #pragma unroll
        for (int d = 0; d < SOM_D; d += 4) {
            float4 wv4 = *(const float4*)(wk + d);
            double w0 = (double)wv4.x, w1 = (double)wv4.y;
            double w2 = (double)wv4.z, w3 = (double)wv4.w;
            s0 += w0 * (w0 - 2.0 * (double)xs[d])     + w2 * (w2 - 2.0 * (double)xs[d + 2]);
            s1 += w1 * (w1 - 2.0 * (double)xs[d + 1]) + w3 * (w3 - 2.0 * (double)xs[d + 3]);
        }
        double sc = s0 + s1;
        int bk = tid;

        #pragma unroll
        for (int off = 32; off > 0; off >>= 1) {
            double os = __shfl_down(sc, off);
            int    ok = __shfl_down(bk, off);
            if (os < sc || (os == sc && ok < bk)) { sc = os; bk = ok; }
        }
        if (lane == 0) { rbest[wv] = sc; rk[wv] = bk; }
        __syncthreads();

        if (tid == 0) {
            double b = rbest[0]; int k0 = rk[0];
            #pragma unroll
            for (int v = 1; v < 16; ++v) {
                if (rbest[v] < b || (rbest[v] == b && rk[v] < k0)) { b = rbest[v]; k0 = rk[v]; }
            }
            rk[0] = k0;
        }
        __syncthreads();
        const int bmu = rk[0];

        out[(size_t)row * SOM_K + tid] = (tid == bmu) ? 1.0f : 0.0f;
    }
}

extern "C" void kernel_launch(void* const* d_in, const int* in_sizes, int n_in,
                              void* d_out, int out_size, void* d_ws, size_t ws_size,
                              hipStream_t stream) {
    const float* x = (const float*)d_in[0];
    const float* w = (const float*)d_in[1];
    float* out = (float*)d_out;

    const int n_samples = in_sizes[0] / SOM_D;  // 100000

    char* ws = (char*)d_ws;
    int*            flag_count = (int*)ws;
    float*          wsq        = (float*)(ws + WS_WSQ);
    unsigned short* w3         = (unsigned short*)(ws + WS_W3);
    int*            flag_list  = (int*)(ws + WS_FLAGS);

    som_prep<<<64, 256, 0, stream>>>(w, w3, wsq, flag_count);
    const int grid = (n_samples + 63) / 64;      // 1563
    som_main<<<grid, 256, 0, stream>>>(x, w3, wsq, out, flag_count, flag_list,
                                       n_samples);
    som_pass2<<<256, 1024, 0, stream>>>(x, w, out, flag_count, flag_list);
}

// Round 13
// 652.160 us; speedup vs baseline: 1.4157x; 1.0142x over previous
//
#include <hip/hip_runtime.h>

// SOM BMU one-hot via split-bf16 MFMA GEMM. R13: DE-CONFOUND round.
// Main's ~250 us is invariant to B-path and TLP fixes (R6/R8/R9/R11/R12 all
// neutral). Theory: the fused 400 MB one-hot write stream thrashes L1/L2
// continuously, so B-tiles never stay resident above L3 (~2000 cyc/tile
// stall derived from R11 counters). "Coalesced B + write-free main" was
// never measured (R5 had split write but broken B; R6 fixed B and fused the
// write simultaneously). R13: main emits bmu[N] only; separate streaming
// writer; pass2 patches bmu before the writer.
//   som_prep : w -> w3 (8-slot swizzled B-frags) + wsq + flag=0
//   som_main : MFMA GEMM -> bmu[] + flags (NO out traffic)
//   som_pass2: fp64 re-solve of flagged rows -> patch bmu[]
//   som_write: one-hot stream from bmu[] (covers all elements, no memset)

typedef __attribute__((ext_vector_type(8))) short bf16x8;   // 8 bf16 = 4 VGPR
typedef __attribute__((ext_vector_type(4))) float f32x4;

#define SOM_K 1024
#define SOM_D 128
#define MARGIN 0.02f
#define FLAG_CAP 8192

// d_ws layout (bytes):
#define WS_WSQ   64        // 1024 f32  (4 KB)
#define WS_W3    8192      // 64 tiles x 8 slots x 64 lanes x 8 bf16 (512 KB)
#define WS_FLAGS 532480    // 8192 int  (32 KB)
#define WS_BMU   565248    // 100000 int (400 KB) -> ends ~966 KB

static __device__ __forceinline__ unsigned short f2bf(float f) {
    unsigned u = __float_as_uint(f);
    return (unsigned short)((u + 0x7FFFu + ((u >> 16) & 1u)) >> 16);  // RNE
}
static __device__ __forceinline__ float bf2f(unsigned short h) {
    return __uint_as_float(((unsigned)h) << 16);
}

// ---- prep: w -> w3 (swizzled split-bf16, 8 slots) + exact wsq + flag=0 ----
__global__ __launch_bounds__(256) void som_prep(
    const float* __restrict__ w, unsigned short* __restrict__ w3,
    float* __restrict__ wsq, int* __restrict__ flag_count)
{
    __shared__ float ws_[16][SOM_D];     // 8 KB staging for 16 protos
    const int nt = blockIdx.x;           // tile 0..63
    const int tid = threadIdx.x;

    if (nt == 0 && tid == 0) *flag_count = 0;

    const float* src = w + (size_t)nt * 16 * SOM_D;
    #pragma unroll
    for (int r = 0; r < 8; ++r) {
        const int e = r * 256 + tid;
        ws_[e >> 7][e & 127] = src[e];
    }
    __syncthreads();

    unsigned short* dst = w3 + (size_t)nt * 4096;
    #pragma unroll
    for (int r = 0; r < 2; ++r) {
        const int G = r * 256 + tid;     // 0..511
        const int s = G >> 6;            // slot 0..7
        const int l = G & 63;            // lane
        const int c = l & 15, q = l >> 4;
        bf16x8 v;
        #pragma unroll
        for (int j = 0; j < 8; ++j) {
            const int kk = 32 * s + 8 * q + j;       // 0..255
            const int d = kk & 127;
            const float f = ws_[c][d];
            const unsigned short h = f2bf(f);
            v[j] = (short)((kk & 128) ? f2bf(f - bf2f(h)) : h);  // wl : wh
        }
        *(bf16x8*)(dst + G * 8) = v;
    }

    if (tid < 16) {
        double s = 0.0;
        #pragma unroll 16
        for (int d = 0; d < SOM_D; ++d) {
            double v = (double)ws_[tid][d];
            s += v * v;
        }
        wsq[nt * 16 + tid] = (float)s;
    }
}

// ---- main: 16 samples/wave, 4 waves/block; MFMA + argmin -> bmu[] ---------
__global__ __launch_bounds__(256) void som_main(
    const float* __restrict__ x,
    const unsigned short* __restrict__ w3,
    const float* __restrict__ wsq,
    int* __restrict__ bmu_out,
    int* __restrict__ flag_count,
    int* __restrict__ flag_list,
    int n_samples)
{
    const int lane = threadIdx.x & 63;
    const int wv   = threadIdx.x >> 6;       // wave 0..3
    const int c = lane & 15;
    const int q = lane >> 4;
    const int R0 = blockIdx.x * 64 + wv * 16;    // 1563 blocks x 64 rows

    // a-frags: A[m=c][k=8q+j], one 16-row group, hi+lo (32 VGPR).
    bf16x8 ah[4], al[4];
    {
        int row = R0 + c;
        if (row >= n_samples) row = n_samples - 1;   // clamp (results unused)
        const float* xp = x + (size_t)row * SOM_D + 8 * q;
        #pragma unroll
        for (int s = 0; s < 4; ++s) {
            float4 v0 = *(const float4*)(xp + 32 * s);
            float4 v1 = *(const float4*)(xp + 32 * s + 4);
            float xv[8] = {v0.x, v0.y, v0.z, v0.w, v1.x, v1.y, v1.z, v1.w};
            bf16x8 hh, ll;
            #pragma unroll
            for (int j = 0; j < 8; ++j) {
                unsigned short h = f2bf(xv[j]);
                hh[j] = (short)h;
                ll[j] = (short)f2bf(xv[j] - bf2f(h));
            }
            ah[s] = hh; al[s] = ll;
        }
    }

    float best[4], sec[4];
    int bk[4];
    #pragma unroll
    for (int r = 0; r < 4; ++r) { best[r] = 1e30f; sec[r] = 1e30f; bk[r] = 0; }

    const unsigned short* wbase = w3 + lane * 8;

    #pragma unroll 1
    for (int nt = 0; nt < 64; ++nt) {
        const int n0 = nt * 16;
        const unsigned short* wp = wbase + (size_t)nt * 4096;
        bf16x8 b[8];
        #pragma unroll
        for (int s = 0; s < 8; ++s) b[s] = *(const bf16x8*)(wp + 512 * s);
        const float wq = wsq[n0 + c];

        f32x4 aA = {0.f, 0.f, 0.f, 0.f}, aB = {0.f, 0.f, 0.f, 0.f};
        #pragma unroll
        for (int s = 0; s < 4; ++s)     // xh * wh
            aA = __builtin_amdgcn_mfma_f32_16x16x32_bf16(ah[s], b[s], aA, 0, 0, 0);
        #pragma unroll
        for (int s = 0; s < 4; ++s)     // xh * wl
            aA = __builtin_amdgcn_mfma_f32_16x16x32_bf16(ah[s], b[4 + s], aA, 0, 0, 0);
        #pragma unroll
        for (int s = 0; s < 4; ++s)     // xl * wh -- reuses b[0..3]
            aB = __builtin_amdgcn_mfma_f32_16x16x32_bf16(al[s], b[s], aB, 0, 0, 0);

        #pragma unroll
        for (int r = 0; r < 4; ++r) {
            float s0 = wq - 2.f * (aA[r] + aB[r]);
            if (s0 < best[r]) { sec[r] = best[r]; best[r] = s0; bk[r] = n0 + c; }
            else if (s0 < sec[r]) sec[r] = s0;
        }
    }

    // reduce across the 16 c-lanes of each quad-group
    #pragma unroll
    for (int r = 0; r < 4; ++r) {
        float b0v = best[r], s0v = sec[r];
        int k0 = bk[r];
        #pragma unroll
        for (int m = 1; m < 16; m <<= 1) {
            float ob = __shfl_xor(b0v, m);
            float os = __shfl_xor(s0v, m);
            int   ok = __shfl_xor(k0, m);
            if (ob < b0v || (ob == b0v && ok < k0)) {
                s0v = fminf(b0v, os); b0v = ob; k0 = ok;
            } else {
                s0v = fminf(s0v, ob);
            }
        }
        best[r] = b0v; sec[r] = s0v; bk[r] = k0;
    }

    if (c == 0) {   // lanes 0,16,32,48 hold rows 4q + r
        #pragma unroll
        for (int r = 0; r < 4; ++r) {
            const int row = R0 + 4 * q + r;
            if (row < n_samples) {
                bmu_out[row] = bk[r];
                if ((sec[r] - best[r]) < MARGIN) {
                    int i = atomicAdd(flag_count, 1);
                    if (i < FLAG_CAP) flag_list[i] = row;
                }
            }
        }
    }
}

// ---- pass2: fp64 re-solve, one 1024-thread block per flagged row ----------
__global__ __launch_bounds__(1024) void som_pass2(
    const float* __restrict__ x,
    const float* __restrict__ w,
    int* __restrict__ bmu_out,
    const int* __restrict__ flag_count,
    const int* __restrict__ flag_list)
{
    __shared__ float xs[SOM_D];
    __shared__ double rbest[16];
    __shared__ int    rk[16];

    const int tid  = threadIdx.x;          // == proto k
    const int lane = tid & 63;
    const int wv   = tid >> 6;             // wave 0..15
    int cnt = *flag_count;
    if (cnt > FLAG_CAP) cnt = FLAG_CAP;

    for (int i = blockIdx.x; i < cnt; i += gridDim.x) {
        const int row = flag_list[i];
        __syncthreads();                   // guard xs/red reuse
        if (tid < SOM_D) xs[tid] = x[(size_t)row * SOM_D + tid];
        __syncthreads();

        const float* wk = w + (size_t)tid * SOM_D;
        double s0 = 0.0, s1 = 0.0;
        #pragma unroll
        for (int d = 0; d < SOM_D; d += 4) {
            float4 wv4 = *(const float4*)(wk + d);
            double w0 = (double)wv4.x, w1 = (double)wv4.y;
            double w2 = (double)wv4.z, w3 = (double)wv4.w;
            s0 += w0 * (w0 - 2.0 * (double)xs[d])     + w2 * (w2 - 2.0 * (double)xs[d + 2]);
            s1 += w1 * (w1 - 2.0 * (double)xs[d + 1]) + w3 * (w3 - 2.0 * (double)xs[d + 3]);
        }
        double sc = s0 + s1;
        int bk = tid;

        #pragma unroll
        for (int off = 32; off > 0; off >>= 1) {
            double os = __shfl_down(sc, off);
            int    ok = __shfl_down(bk, off);
            if (os < sc || (os == sc && ok < bk)) { sc = os; bk = ok; }
        }
        if (lane == 0) { rbest[wv] = sc; rk[wv] = bk; }
        __syncthreads();

        if (tid == 0) {
            double b = rbest[0]; int k0 = rk[0];
            #pragma unroll
            for (int v = 1; v < 16; ++v) {
                if (rbest[v] < b || (rbest[v] == b && rk[v] < k0)) { b = rbest[v]; k0 = rk[v]; }
            }
            bmu_out[row] = k0;             // patch bmu only
        }
        __syncthreads();
    }
}

// ---- writer: streaming one-hot from bmu[], covers every element -----------
__global__ __launch_bounds__(256) void som_write(
    float* __restrict__ out, const int* __restrict__ bmu, int n)
{
    const int lane = threadIdx.x & 63;
    const int wv   = threadIdx.x >> 6;
    int row = blockIdx.x * 4 + wv;
    const int stride = gridDim.x * 4;

    for (; row < n; row += stride) {
        const int b = bmu[row];
        f32x4* op = (f32x4*)(out + (size_t)row * SOM_K);
        #pragma unroll
        for (int j = 0; j < 4; ++j) {
            const int e = j * 64 + lane;
            f32x4 v = {0.f, 0.f, 0.f, 0.f};
            if ((b >> 2) == e) v[b & 3] = 1.0f;
            op[e] = v;
        }
    }
}

extern "C" void kernel_launch(void* const* d_in, const int* in_sizes, int n_in,
                              void* d_out, int out_size, void* d_ws, size_t ws_size,
                              hipStream_t stream) {
    const float* x = (const float*)d_in[0];
    const float* w = (const float*)d_in[1];
    float* out = (float*)d_out;

    const int n_samples = in_sizes[0] / SOM_D;  // 100000

    char* ws = (char*)d_ws;
    int*            flag_count = (int*)ws;
    float*          wsq        = (float*)(ws + WS_WSQ);
    unsigned short* w3         = (unsigned short*)(ws + WS_W3);
    int*            flag_list  = (int*)(ws + WS_FLAGS);
    int*            bmu        = (int*)(ws + WS_BMU);

    som_prep<<<64, 256, 0, stream>>>(w, w3, wsq, flag_count);
    const int grid = (n_samples + 63) / 64;      // 1563
    som_main<<<grid, 256, 0, stream>>>(x, w3, wsq, bmu, flag_count, flag_list,
                                       n_samples);
    som_pass2<<<256, 1024, 0, stream>>>(x, w, bmu, flag_count, flag_list);
    som_write<<<1024, 256, 0, stream>>>(out, bmu, n_samples);
}